// Round 1
// baseline (1807.307 us; speedup 1.0000x reference)
//
#include <hip/hip_runtime.h>
#include <hip/hip_bf16.h>
#include <math.h>

#define NTOK 384
#define HEADS 4

// ---------------------------------------------------------------------------
// Tiled fp32 GEMM, C = A (MxK) * B^T (NxK) + bias, optional relu.
// Batched over blockIdx.z with element strides sA/sB/sC.
// BM=BN=64, BK=16, 256 threads, 4x4 micro-tile per thread.
// ---------------------------------------------------------------------------
#define BM 64
#define BN 64
#define BK 16

__global__ __launch_bounds__(256) void gemm_nt(
    const float* __restrict__ A, const float* __restrict__ B,
    const float* __restrict__ bias, float* __restrict__ C,
    int M, int N, int K, int lda, int ldb, int ldc,
    long sA, long sB, long sC, int relu)
{
    __shared__ float As[BK][BM + 4];
    __shared__ float Bs[BK][BN + 4];
    A += (long)blockIdx.z * sA;
    B += (long)blockIdx.z * sB;
    C += (long)blockIdx.z * sC;
    const int row0 = blockIdx.y * BM;
    const int col0 = blockIdx.x * BN;
    const int tid = threadIdx.x;
    const int tx = tid & 15, ty = tid >> 4;

    float acc[4][4] = {};

    for (int k0 = 0; k0 < K; k0 += BK) {
        #pragma unroll
        for (int i = 0; i < 4; ++i) {
            int idx = tid + i * 256;          // 0..1023
            int m = idx >> 4, kk = idx & 15;
            As[kk][m] = A[(long)(row0 + m) * lda + k0 + kk];
        }
        #pragma unroll
        for (int i = 0; i < 4; ++i) {
            int idx = tid + i * 256;
            int n = idx >> 4, kk = idx & 15;
            Bs[kk][n] = B[(long)(col0 + n) * ldb + k0 + kk];
        }
        __syncthreads();
        #pragma unroll
        for (int kk = 0; kk < BK; ++kk) {
            float4 av = *reinterpret_cast<const float4*>(&As[kk][ty * 4]);
            float4 bv = *reinterpret_cast<const float4*>(&Bs[kk][tx * 4]);
            float a[4] = {av.x, av.y, av.z, av.w};
            float b[4] = {bv.x, bv.y, bv.z, bv.w};
            #pragma unroll
            for (int i = 0; i < 4; ++i)
                #pragma unroll
                for (int j = 0; j < 4; ++j)
                    acc[i][j] = fmaf(a[i], b[j], acc[i][j]);
        }
        __syncthreads();
    }

    #pragma unroll
    for (int i = 0; i < 4; ++i) {
        int r = row0 + ty * 4 + i;
        #pragma unroll
        for (int j = 0; j < 4; ++j) {
            int cidx = col0 + tx * 4 + j;
            float v = acc[i][j];
            if (bias) v += bias[cidx];
            if (relu) v = fmaxf(v, 0.f);
            C[(long)r * ldc + cidx] = v;
        }
    }
}

// C = A (MxK) * B (KxN)   (B row-major, not transposed). Batched via z.
__global__ __launch_bounds__(256) void gemm_nn(
    const float* __restrict__ A, const float* __restrict__ B,
    float* __restrict__ C,
    int M, int N, int K, int lda, int ldb, int ldc,
    long sA, long sB, long sC)
{
    __shared__ float As[BK][BM + 4];
    __shared__ float Bs[BK][BN + 4];
    A += (long)blockIdx.z * sA;
    B += (long)blockIdx.z * sB;
    C += (long)blockIdx.z * sC;
    const int row0 = blockIdx.y * BM;
    const int col0 = blockIdx.x * BN;
    const int tid = threadIdx.x;
    const int tx = tid & 15, ty = tid >> 4;

    float acc[4][4] = {};

    for (int k0 = 0; k0 < K; k0 += BK) {
        #pragma unroll
        for (int i = 0; i < 4; ++i) {
            int idx = tid + i * 256;
            int m = idx >> 4, kk = idx & 15;
            As[kk][m] = A[(long)(row0 + m) * lda + k0 + kk];
        }
        #pragma unroll
        for (int i = 0; i < 4; ++i) {
            int idx = tid + i * 256;        // n fastest for coalescing
            int n = idx & 63, kk = idx >> 6;
            Bs[kk][n] = B[(long)(k0 + kk) * ldb + col0 + n];
        }
        __syncthreads();
        #pragma unroll
        for (int kk = 0; kk < BK; ++kk) {
            float4 av = *reinterpret_cast<const float4*>(&As[kk][ty * 4]);
            float4 bv = *reinterpret_cast<const float4*>(&Bs[kk][tx * 4]);
            float a[4] = {av.x, av.y, av.z, av.w};
            float b[4] = {bv.x, bv.y, bv.z, bv.w};
            #pragma unroll
            for (int i = 0; i < 4; ++i)
                #pragma unroll
                for (int j = 0; j < 4; ++j)
                    acc[i][j] = fmaf(a[i], b[j], acc[i][j]);
        }
        __syncthreads();
    }

    #pragma unroll
    for (int i = 0; i < 4; ++i) {
        int r = row0 + ty * 4 + i;
        #pragma unroll
        for (int j = 0; j < 4; ++j)
            C[(long)r * ldc + col0 + tx * 4 + j] = acc[i][j];
    }
}

// ---------------------------------------------------------------------------
// Softmax over rows of length 384 (one wave per row), with pre-scale.
// ---------------------------------------------------------------------------
__global__ __launch_bounds__(64) void softmax_rows(float* __restrict__ S, float scale)
{
    float* p = S + (long)blockIdx.x * NTOK;
    const int t = threadIdx.x;
    float vals[6];
    float vmax = -1e30f;
    #pragma unroll
    for (int i = 0; i < 6; ++i) {
        vals[i] = p[t + i * 64] * scale;
        vmax = fmaxf(vmax, vals[i]);
    }
    for (int off = 32; off; off >>= 1) vmax = fmaxf(vmax, __shfl_down(vmax, off));
    vmax = __shfl(vmax, 0);
    float sum = 0.f;
    #pragma unroll
    for (int i = 0; i < 6; ++i) { vals[i] = __expf(vals[i] - vmax); sum += vals[i]; }
    for (int off = 32; off; off >>= 1) sum += __shfl_down(sum, off);
    sum = __shfl(sum, 0);
    float inv = 1.f / sum;
    #pragma unroll
    for (int i = 0; i < 6; ++i) p[t + i * 64] = vals[i] * inv;
}

// ---------------------------------------------------------------------------
// x = LayerNorm(x + y) * s + b   (row per block)
// ---------------------------------------------------------------------------
__global__ __launch_bounds__(256) void add_ln(
    float* __restrict__ x, const float* __restrict__ y,
    const float* __restrict__ s, const float* __restrict__ b, int d)
{
    float* xr = x + (long)blockIdx.x * d;
    const float* yr = y + (long)blockIdx.x * d;
    const int t = threadIdx.x;
    float s1 = 0.f, s2 = 0.f;
    for (int i = t; i < d; i += 256) {
        float v = xr[i] + yr[i];
        s1 += v; s2 += v * v;
    }
    for (int off = 32; off; off >>= 1) { s1 += __shfl_down(s1, off); s2 += __shfl_down(s2, off); }
    __shared__ float r1[4], r2[4];
    int w = t >> 6;
    if ((t & 63) == 0) { r1[w] = s1; r2[w] = s2; }
    __syncthreads();
    if (t == 0) {
        float a = 0.f, c = 0.f;
        for (int i = 0; i < 4; ++i) { a += r1[i]; c += r2[i]; }
        r1[0] = a; r2[0] = c;
    }
    __syncthreads();
    float mean = r1[0] / d;
    float var = r2[0] / d - mean * mean;
    float rstd = rsqrtf(var + 1e-5f);
    for (int i = t; i < d; i += 256) {
        float v = xr[i] + yr[i];
        xr[i] = (v - mean) * rstd * s[i] + b[i];
    }
}

// ---------------------------------------------------------------------------
// misc small kernels
// ---------------------------------------------------------------------------
__global__ void copy_k(const float* __restrict__ src, float* __restrict__ dst, int n)
{
    int i = blockIdx.x * blockDim.x + threadIdx.x;
    if (i < n) dst[i] = src[i];
}

__global__ void concat_k(const float* __restrict__ te, const float* __restrict__ ve,
                         float* __restrict__ all)
{
    int i = blockIdx.x * blockDim.x + threadIdx.x;
    if (i >= NTOK * 1536) return;
    int r = i / 1536, c = i % 1536;
    all[i] = (c < 768) ? te[r * 768 + c] : ve[r * 768 + (c - 768)];
}

// a[i,cls], c[i,cls] from all_emb row i (d=1536)
__global__ __launch_bounds__(256) void head_ac(
    const float* __restrict__ all, const float* __restrict__ lin_w,
    const float* __restrict__ lin_b, float* __restrict__ a, float* __restrict__ c)
{
    const int i = blockIdx.x, t = threadIdx.x;
    const float* xr = all + (long)i * 1536;
    float s0 = 0.f, s1 = 0.f, s2 = 0.f, s3 = 0.f;
    for (int e = t; e < 1536; e += 256) {
        float v = xr[e];
        s0 += v * lin_w[e];            // a, cls 0
        s1 += v * lin_w[3072 + e];     // a, cls 1
        s2 += v * lin_w[1536 + e];     // c, cls 0
        s3 += v * lin_w[4608 + e];     // c, cls 1
    }
    for (int off = 32; off; off >>= 1) {
        s0 += __shfl_down(s0, off); s1 += __shfl_down(s1, off);
        s2 += __shfl_down(s2, off); s3 += __shfl_down(s3, off);
    }
    __shared__ float r[4][4];
    int w = t >> 6;
    if ((t & 63) == 0) { r[0][w] = s0; r[1][w] = s1; r[2][w] = s2; r[3][w] = s3; }
    __syncthreads();
    if (t == 0) {
        float t0 = 0.f, t1 = 0.f, t2 = 0.f, t3 = 0.f;
        for (int k = 0; k < 4; ++k) { t0 += r[0][k]; t1 += r[1][k]; t2 += r[2][k]; t3 += r[3][k]; }
        a[i * 2 + 0] = t0 + lin_b[0];
        a[i * 2 + 1] = t1 + lin_b[1];
        c[i * 2 + 0] = t2;
        c[i * 2 + 1] = t3;
    }
}

// probs[i,j,:], per-row cls-loss partial, per-row link sum. block=row i, 384 thr.
__global__ __launch_bounds__(384) void head_probs(
    const float* __restrict__ a, const float* __restrict__ c,
    const int* __restrict__ gt, float* __restrict__ probs,
    float* __restrict__ rowsum, float* __restrict__ rowcell)
{
    const int i = blockIdx.x, j = threadIdx.x;
    float l0 = a[i * 2 + 0] + c[j * 2 + 0];
    float l1 = a[i * 2 + 1] + c[j * 2 + 1];
    float m = fmaxf(l0, l1);
    float e0 = __expf(l0 - m), e1 = __expf(l1 - m);
    float inv = 1.f / (e0 + e1);
    float p0 = e0 * inv, p1 = e1 * inv;
    long base = ((long)i * NTOK + j) * 2;
    probs[base] = p0;
    probs[base + 1] = p1;
    // log_softmax applied to (p0, p1), per reference
    float m2 = fmaxf(p0, p1);
    float z = m2 + __logf(__expf(p0 - m2) + __expf(p1 - m2));
    int g = gt[i * NTOK + j];
    float cell = z - (g ? p1 : p0);
    float cs = cell, ps = p1;
    for (int off = 32; off; off >>= 1) { cs += __shfl_down(cs, off); ps += __shfl_down(ps, off); }
    __shared__ float rc[6], rs[6];
    int w = j >> 6;
    if ((j & 63) == 0) { rc[w] = cs; rs[w] = ps; }
    __syncthreads();
    if (j == 0) {
        float csum = 0.f, psum = 0.f;
        for (int k = 0; k < 6; ++k) { csum += rc[k]; psum += rs[k]; }
        rowcell[i] = csum * (1.f / NTOK);
        rowsum[i] = psum;
    }
}

__global__ __launch_bounds__(64) void colsum_k(const float* __restrict__ probs,
                                               float* __restrict__ colsum)
{
    const int j = blockIdx.x, t = threadIdx.x;
    float s = 0.f;
    for (int i = t; i < NTOK; i += 64)
        s += probs[((long)i * NTOK + j) * 2 + 1];
    for (int off = 32; off; off >>= 1) s += __shfl_down(s, off);
    if (t == 0) colsum[j] = s;
}

__global__ __launch_bounds__(384) void finalize_k(
    const float* __restrict__ rowcell, const float* __restrict__ rowsum,
    const float* __restrict__ colsum, float* __restrict__ out)
{
    const int t = threadIdx.x;
    float cls = rowcell[t];
    float ee = (t < NTOK - 1) ? fabsf(rowsum[t] + colsum[t] - 1.f) : 0.f;
    for (int off = 32; off; off >>= 1) { cls += __shfl_down(cls, off); ee += __shfl_down(ee, off); }
    __shared__ float rc[6], re[6];
    int w = t >> 6;
    if ((t & 63) == 0) { rc[w] = cls; re[w] = ee; }
    __syncthreads();
    if (t == 0) {
        float a = 0.f, b = 0.f;
        for (int k = 0; k < 6; ++k) { a += rc[k]; b += re[k]; }
        out[NTOK * NTOK * 2 + 0] = a;
        out[NTOK * NTOK * 2 + 1] = b;
    }
}

// ---------------------------------------------------------------------------
// host-side encoder driver
// ---------------------------------------------------------------------------
static void run_encoder(float* x, int d,
                        const float* qkv_w, const float* qkv_b,
                        const float* out_w, const float* out_b,
                        const float* ln1_s, const float* ln1_b,
                        const float* ff1_w, const float* ff1_b,
                        const float* ff2_w, const float* ff2_b,
                        const float* ln2_s, const float* ln2_b,
                        float* qkv, float* sc, float* o, float* t1, float* t2,
                        hipStream_t stream)
{
    const int M = NTOK;
    const int dq = 3 * d;
    const int hd = d / HEADS;
    const float scale = 1.0f / sqrtf((float)hd);
    for (int l = 0; l < 2; ++l) {
        const float* Wqkv = qkv_w + (long)l * dq * d;
        // qkv = x @ Wqkv^T + b
        gemm_nt<<<dim3(dq / 64, M / 64, 1), 256, 0, stream>>>(
            x, Wqkv, qkv_b + l * dq, qkv, M, dq, d, d, d, dq, 0, 0, 0, 0);
        // scores[h] = q[h] @ k[h]^T   (batched over heads)
        gemm_nt<<<dim3(NTOK / 64, M / 64, HEADS), 256, 0, stream>>>(
            qkv, qkv + d, nullptr, sc, M, NTOK, hd, dq, dq, NTOK,
            (long)hd, (long)hd, (long)NTOK * NTOK, 0);
        softmax_rows<<<HEADS * NTOK, 64, 0, stream>>>(sc, scale);
        // o[h] = attn[h] @ v[h]
        gemm_nn<<<dim3(hd / 64, M / 64, HEADS), 256, 0, stream>>>(
            sc, qkv + 2 * d, o, M, hd, NTOK, NTOK, dq, d,
            (long)NTOK * NTOK, (long)hd, (long)hd);
        // t2 = o @ out_w^T + out_b ; x = LN(x + t2)
        gemm_nt<<<dim3(d / 64, M / 64, 1), 256, 0, stream>>>(
            o, out_w + (long)l * d * d, out_b + l * d, t2, M, d, d, d, d, d, 0, 0, 0, 0);
        add_ln<<<M, 256, 0, stream>>>(x, t2, ln1_s + l * d, ln1_b + l * d, d);
        // t1 = relu(x @ ff1_w^T + b1); t2 = t1 @ ff2_w^T + b2; x = LN(x + t2)
        gemm_nt<<<dim3(2048 / 64, M / 64, 1), 256, 0, stream>>>(
            x, ff1_w + (long)l * 2048 * d, ff1_b + l * 2048, t1, M, 2048, d, d, d, 2048, 0, 0, 0, 1);
        gemm_nt<<<dim3(d / 64, M / 64, 1), 256, 0, stream>>>(
            t1, ff2_w + (long)l * d * 2048, ff2_b + l * d, t2, M, d, 2048, 2048, 2048, d, 0, 0, 0, 0);
        add_ln<<<M, 256, 0, stream>>>(x, t2, ln2_s + l * d, ln2_b + l * d, d);
    }
}

extern "C" void kernel_launch(void* const* d_in, const int* in_sizes, int n_in,
                              void* d_out, int out_size, void* d_ws, size_t ws_size,
                              hipStream_t stream)
{
    const float* text_emb   = (const float*)d_in[0];
    const float* vision_emb = (const float*)d_in[1];
    const int*   gt         = (const int*)  d_in[2];
    const float* t_qkv_w = (const float*)d_in[3];
    const float* t_qkv_b = (const float*)d_in[4];
    const float* t_out_w = (const float*)d_in[5];
    const float* t_out_b = (const float*)d_in[6];
    const float* t_ln1_s = (const float*)d_in[7];
    const float* t_ln1_b = (const float*)d_in[8];
    const float* t_ff1_w = (const float*)d_in[9];
    const float* t_ff1_b = (const float*)d_in[10];
    const float* t_ff2_w = (const float*)d_in[11];
    const float* t_ff2_b = (const float*)d_in[12];
    const float* t_ln2_s = (const float*)d_in[13];
    const float* t_ln2_b = (const float*)d_in[14];
    const float* c_qkv_w = (const float*)d_in[15];
    const float* c_qkv_b = (const float*)d_in[16];
    const float* c_out_w = (const float*)d_in[17];
    const float* c_out_b = (const float*)d_in[18];
    const float* c_ln1_s = (const float*)d_in[19];
    const float* c_ln1_b = (const float*)d_in[20];
    const float* c_ff1_w = (const float*)d_in[21];
    const float* c_ff1_b = (const float*)d_in[22];
    const float* c_ff2_w = (const float*)d_in[23];
    const float* c_ff2_b = (const float*)d_in[24];
    const float* c_ln2_s = (const float*)d_in[25];
    const float* c_ln2_b = (const float*)d_in[26];
    const float* lin_w   = (const float*)d_in[27];
    const float* lin_b   = (const float*)d_in[28];
    float* out = (float*)d_out;

    // workspace layout (floats)
    float* ws = (float*)d_ws;
    float* xt      = ws;                 // 384*768
    float* all     = xt + 294912;        // 384*1536
    float* qkv     = all + 589824;       // 384*4608 (max)
    float* sc      = qkv + 1769472;      // 4*384*384
    float* o       = sc + 589824;        // 384*1536 (max)
    float* t1      = o + 589824;         // 384*2048
    float* t2      = t1 + 786432;        // 384*1536 (max)
    float* abuf    = t2 + 589824;        // 384*2
    float* cbuf    = abuf + 768;         // 384*2
    float* rowsum  = cbuf + 768;         // 384
    float* rowcell = rowsum + 384;       // 384
    float* colsum  = rowcell + 384;      // 384

    // text encoder (d = 768)
    copy_k<<<(294912 + 255) / 256, 256, 0, stream>>>(text_emb, xt, 294912);
    run_encoder(xt, 768,
                t_qkv_w, t_qkv_b, t_out_w, t_out_b, t_ln1_s, t_ln1_b,
                t_ff1_w, t_ff1_b, t_ff2_w, t_ff2_b, t_ln2_s, t_ln2_b,
                qkv, sc, o, t1, t2, stream);

    // concat -> combined encoder (d = 1536)
    concat_k<<<(589824 + 255) / 256, 256, 0, stream>>>(xt, vision_emb, all);
    run_encoder(all, 1536,
                c_qkv_w, c_qkv_b, c_out_w, c_out_b, c_ln1_s, c_ln1_b,
                c_ff1_w, c_ff1_b, c_ff2_w, c_ff2_b, c_ln2_s, c_ln2_b,
                qkv, sc, o, t1, t2, stream);

    // head
    head_ac<<<NTOK, 256, 0, stream>>>(all, lin_w, lin_b, abuf, cbuf);
    head_probs<<<NTOK, 384, 0, stream>>>(abuf, cbuf, gt, out, rowsum, rowcell);
    colsum_k<<<NTOK, 64, 0, stream>>>(out, colsum);
    finalize_k<<<1, 384, 0, stream>>>(rowcell, rowsum, colsum, out);
}

// Round 2
// 769.763 us; speedup vs baseline: 2.3479x; 2.3479x over previous
//
#include <hip/hip_runtime.h>
#include <hip/hip_bf16.h>
#include <math.h>

#define NTOK 384
#define HEADS 4

typedef __attribute__((ext_vector_type(8))) short bf16x8;
typedef __attribute__((ext_vector_type(4))) float f32x4;

__device__ __forceinline__ unsigned short f2b(float f) {
    union { float f; unsigned int u; } v; v.f = f;
    unsigned int r = (v.u + 0x7fff + ((v.u >> 16) & 1)) >> 16;  // RNE
    return (unsigned short)r;
}

// ---------------------------------------------------------------------------
// MFMA bf16 GEMM: C = A (MxK, bf16, row-major) @ B^T (B is NxK bf16 row-major)
// + bias(fp32, optional), optional relu, fp32 or bf16 output.
// Block = 256 threads = 4 waves in 2x2; each wave owns a 32x32 output tile
// (2x2 MFMA 16x16x32 tiles). Fragments loaded directly from global (16B).
// ---------------------------------------------------------------------------
__global__ __launch_bounds__(256) void gemm_mfma_nt(
    const unsigned short* __restrict__ A, const unsigned short* __restrict__ B,
    const float* __restrict__ bias, void* __restrict__ Cv,
    int M, int N, int K, int lda, int ldb, int ldc,
    long sA, long sB, long sC, int relu, int out_bf16)
{
    A += (long)blockIdx.z * sA;
    B += (long)blockIdx.z * sB;
    const int lane = threadIdx.x & 63;
    const int wid  = threadIdx.x >> 6;
    const int wm = wid >> 1, wn = wid & 1;
    const int r16 = lane & 15, quad = lane >> 4;
    const int row0 = blockIdx.y * 64 + wm * 32;
    const int col0 = blockIdx.x * 64 + wn * 32;

    f32x4 acc00 = {}, acc01 = {}, acc10 = {}, acc11 = {};

    const unsigned short* Ar0 = A + (long)(row0 + r16) * lda + quad * 8;
    const unsigned short* Ar1 = Ar0 + 16 * lda;
    const unsigned short* Br0 = B + (long)(col0 + r16) * ldb + quad * 8;
    const unsigned short* Br1 = Br0 + 16 * ldb;

    for (int k0 = 0; k0 < K; k0 += 32) {
        bf16x8 a0 = *reinterpret_cast<const bf16x8*>(Ar0 + k0);
        bf16x8 a1 = *reinterpret_cast<const bf16x8*>(Ar1 + k0);
        bf16x8 b0 = *reinterpret_cast<const bf16x8*>(Br0 + k0);
        bf16x8 b1 = *reinterpret_cast<const bf16x8*>(Br1 + k0);
        acc00 = __builtin_amdgcn_mfma_f32_16x16x32_bf16(a0, b0, acc00, 0, 0, 0);
        acc01 = __builtin_amdgcn_mfma_f32_16x16x32_bf16(a0, b1, acc01, 0, 0, 0);
        acc10 = __builtin_amdgcn_mfma_f32_16x16x32_bf16(a1, b0, acc10, 0, 0, 0);
        acc11 = __builtin_amdgcn_mfma_f32_16x16x32_bf16(a1, b1, acc11, 0, 0, 0);
    }

    float* Cf = (float*)Cv;
    unsigned short* Cb = (unsigned short*)Cv;
    const long zoff = (long)blockIdx.z * sC;
    f32x4 accs[2][2] = {{acc00, acc01}, {acc10, acc11}};
    #pragma unroll
    for (int mt = 0; mt < 2; ++mt) {
        #pragma unroll
        for (int nt = 0; nt < 2; ++nt) {
            f32x4 v = accs[mt][nt];
            int col = col0 + nt * 16 + r16;
            float bi = bias ? bias[col] : 0.f;
            #pragma unroll
            for (int i = 0; i < 4; ++i) {
                int row = row0 + mt * 16 + quad * 4 + i;
                float val = v[i] + bi;
                if (relu) val = fmaxf(val, 0.f);
                long off = zoff + (long)row * ldc + col;
                if (out_bf16) Cb[off] = f2b(val);
                else          Cf[off] = val;
            }
        }
    }
}

// ---------------------------------------------------------------------------
// Fused fp32 -> bf16 conversion of all 8 weight tensors (hardcoded sizes).
// ---------------------------------------------------------------------------
#define WO0 0u
#define WO1 3538944u
#define WO2 4718592u
#define WO3 7864320u
#define WO4 11010048u
#define WO5 25165824u
#define WO6 29884416u
#define WO7 36175872u
#define WTOT 42467328u

__global__ __launch_bounds__(256) void convert_weights(
    const float* __restrict__ s0, const float* __restrict__ s1,
    const float* __restrict__ s2, const float* __restrict__ s3,
    const float* __restrict__ s4, const float* __restrict__ s5,
    const float* __restrict__ s6, const float* __restrict__ s7,
    unsigned short* __restrict__ dst)
{
    unsigned int e = (blockIdx.x * 256u + threadIdx.x) * 4u;
    if (e >= WTOT) return;
    const float* src; unsigned int local;
    if      (e < WO1) { src = s0; local = e - WO0; }
    else if (e < WO2) { src = s1; local = e - WO1; }
    else if (e < WO3) { src = s2; local = e - WO2; }
    else if (e < WO4) { src = s3; local = e - WO3; }
    else if (e < WO5) { src = s4; local = e - WO4; }
    else if (e < WO6) { src = s5; local = e - WO5; }
    else if (e < WO7) { src = s6; local = e - WO6; }
    else              { src = s7; local = e - WO7; }
    float4 v = *reinterpret_cast<const float4*>(src + local);
    ushort4 o;
    o.x = f2b(v.x); o.y = f2b(v.y); o.z = f2b(v.z); o.w = f2b(v.w);
    *reinterpret_cast<ushort4*>(dst + e) = o;
}

// ---------------------------------------------------------------------------
// Softmax over rows of length 384 (one wave per row); fp32 in, bf16 out.
// ---------------------------------------------------------------------------
__global__ __launch_bounds__(64) void softmax_rows(
    const float* __restrict__ S, unsigned short* __restrict__ P, float scale)
{
    const float* p = S + (long)blockIdx.x * NTOK;
    unsigned short* q = P + (long)blockIdx.x * NTOK;
    const int t = threadIdx.x;
    float vals[6];
    float vmax = -1e30f;
    #pragma unroll
    for (int i = 0; i < 6; ++i) {
        vals[i] = p[t + i * 64] * scale;
        vmax = fmaxf(vmax, vals[i]);
    }
    for (int off = 32; off; off >>= 1) vmax = fmaxf(vmax, __shfl_down(vmax, off));
    vmax = __shfl(vmax, 0);
    float sum = 0.f;
    #pragma unroll
    for (int i = 0; i < 6; ++i) { vals[i] = __expf(vals[i] - vmax); sum += vals[i]; }
    for (int off = 32; off; off >>= 1) sum += __shfl_down(sum, off);
    sum = __shfl(sum, 0);
    float inv = 1.f / sum;
    #pragma unroll
    for (int i = 0; i < 6; ++i) q[t + i * 64] = f2b(vals[i] * inv);
}

// ---------------------------------------------------------------------------
// vT[c][t] = qkv[t][2d + c]  (bf16 transpose of the V block), LDS-tiled.
// block (32,32); grid (d/32, NTOK/32)
// ---------------------------------------------------------------------------
__global__ void transpose_v(const unsigned short* __restrict__ qkv,
                            unsigned short* __restrict__ vt, int d)
{
    __shared__ unsigned short tile[32][33];
    int c0 = blockIdx.x * 32, t0 = blockIdx.y * 32;
    int tx = threadIdx.x, ty = threadIdx.y;
    tile[ty][tx] = qkv[(long)(t0 + ty) * (3 * d) + 2 * d + c0 + tx];
    __syncthreads();
    vt[(long)(c0 + ty) * NTOK + t0 + tx] = tile[tx][ty];
}

// ---------------------------------------------------------------------------
// x = LayerNorm(x + y) * s + b  (fp32), also writes bf16 copy xb.
// ---------------------------------------------------------------------------
__global__ __launch_bounds__(256) void add_ln(
    float* __restrict__ x, unsigned short* __restrict__ xb,
    const float* __restrict__ y,
    const float* __restrict__ s, const float* __restrict__ b, int d)
{
    float* xr = x + (long)blockIdx.x * d;
    unsigned short* xbr = xb + (long)blockIdx.x * d;
    const float* yr = y + (long)blockIdx.x * d;
    const int t = threadIdx.x;
    float s1 = 0.f, s2 = 0.f;
    for (int i = t; i < d; i += 256) {
        float v = xr[i] + yr[i];
        s1 += v; s2 += v * v;
    }
    for (int off = 32; off; off >>= 1) { s1 += __shfl_down(s1, off); s2 += __shfl_down(s2, off); }
    __shared__ float r1[4], r2[4];
    int w = t >> 6;
    if ((t & 63) == 0) { r1[w] = s1; r2[w] = s2; }
    __syncthreads();
    if (t == 0) {
        float a = 0.f, c = 0.f;
        for (int i = 0; i < 4; ++i) { a += r1[i]; c += r2[i]; }
        r1[0] = a; r2[0] = c;
    }
    __syncthreads();
    float mean = r1[0] / d;
    float var = r2[0] / d - mean * mean;
    float rstd = rsqrtf(var + 1e-5f);
    for (int i = t; i < d; i += 256) {
        float v = (xr[i] + yr[i] - mean) * rstd * s[i] + b[i];
        xr[i] = v;
        xbr[i] = f2b(v);
    }
}

// ---------------------------------------------------------------------------
// init / concat (write fp32 + bf16 copies)
// ---------------------------------------------------------------------------
__global__ void initx_k(const float* __restrict__ src, float* __restrict__ dst,
                        unsigned short* __restrict__ dstb, int n)
{
    int i = blockIdx.x * blockDim.x + threadIdx.x;
    if (i < n) { float v = src[i]; dst[i] = v; dstb[i] = f2b(v); }
}

__global__ void concat_k(const float* __restrict__ te, const float* __restrict__ ve,
                         float* __restrict__ all, unsigned short* __restrict__ allb)
{
    int i = blockIdx.x * blockDim.x + threadIdx.x;
    if (i >= NTOK * 1536) return;
    int r = i / 1536, c = i % 1536;
    float v = (c < 768) ? te[r * 768 + c] : ve[r * 768 + (c - 768)];
    all[i] = v;
    allb[i] = f2b(v);
}

// ---------------------------------------------------------------------------
// head kernels (fp32, unchanged from round 0)
// ---------------------------------------------------------------------------
__global__ __launch_bounds__(256) void head_ac(
    const float* __restrict__ all, const float* __restrict__ lin_w,
    const float* __restrict__ lin_b, float* __restrict__ a, float* __restrict__ c)
{
    const int i = blockIdx.x, t = threadIdx.x;
    const float* xr = all + (long)i * 1536;
    float s0 = 0.f, s1 = 0.f, s2 = 0.f, s3 = 0.f;
    for (int e = t; e < 1536; e += 256) {
        float v = xr[e];
        s0 += v * lin_w[e];
        s1 += v * lin_w[3072 + e];
        s2 += v * lin_w[1536 + e];
        s3 += v * lin_w[4608 + e];
    }
    for (int off = 32; off; off >>= 1) {
        s0 += __shfl_down(s0, off); s1 += __shfl_down(s1, off);
        s2 += __shfl_down(s2, off); s3 += __shfl_down(s3, off);
    }
    __shared__ float r[4][4];
    int w = t >> 6;
    if ((t & 63) == 0) { r[0][w] = s0; r[1][w] = s1; r[2][w] = s2; r[3][w] = s3; }
    __syncthreads();
    if (t == 0) {
        float t0 = 0.f, t1 = 0.f, t2 = 0.f, t3 = 0.f;
        for (int k = 0; k < 4; ++k) { t0 += r[0][k]; t1 += r[1][k]; t2 += r[2][k]; t3 += r[3][k]; }
        a[i * 2 + 0] = t0 + lin_b[0];
        a[i * 2 + 1] = t1 + lin_b[1];
        c[i * 2 + 0] = t2;
        c[i * 2 + 1] = t3;
    }
}

__global__ __launch_bounds__(384) void head_probs(
    const float* __restrict__ a, const float* __restrict__ c,
    const int* __restrict__ gt, float* __restrict__ probs,
    float* __restrict__ rowsum, float* __restrict__ rowcell)
{
    const int i = blockIdx.x, j = threadIdx.x;
    float l0 = a[i * 2 + 0] + c[j * 2 + 0];
    float l1 = a[i * 2 + 1] + c[j * 2 + 1];
    float m = fmaxf(l0, l1);
    float e0 = __expf(l0 - m), e1 = __expf(l1 - m);
    float inv = 1.f / (e0 + e1);
    float p0 = e0 * inv, p1 = e1 * inv;
    long base = ((long)i * NTOK + j) * 2;
    probs[base] = p0;
    probs[base + 1] = p1;
    float m2 = fmaxf(p0, p1);
    float z = m2 + __logf(__expf(p0 - m2) + __expf(p1 - m2));
    int g = gt[i * NTOK + j];
    float cell = z - (g ? p1 : p0);
    float cs = cell, ps = p1;
    for (int off = 32; off; off >>= 1) { cs += __shfl_down(cs, off); ps += __shfl_down(ps, off); }
    __shared__ float rc[6], rs[6];
    int w = j >> 6;
    if ((j & 63) == 0) { rc[w] = cs; rs[w] = ps; }
    __syncthreads();
    if (j == 0) {
        float csum = 0.f, psum = 0.f;
        for (int k = 0; k < 6; ++k) { csum += rc[k]; psum += rs[k]; }
        rowcell[i] = csum * (1.f / NTOK);
        rowsum[i] = psum;
    }
}

__global__ __launch_bounds__(64) void colsum_k(const float* __restrict__ probs,
                                               float* __restrict__ colsum)
{
    const int j = blockIdx.x, t = threadIdx.x;
    float s = 0.f;
    for (int i = t; i < NTOK; i += 64)
        s += probs[((long)i * NTOK + j) * 2 + 1];
    for (int off = 32; off; off >>= 1) s += __shfl_down(s, off);
    if (t == 0) colsum[j] = s;
}

__global__ __launch_bounds__(384) void finalize_k(
    const float* __restrict__ rowcell, const float* __restrict__ rowsum,
    const float* __restrict__ colsum, float* __restrict__ out)
{
    const int t = threadIdx.x;
    float cls = rowcell[t];
    float ee = (t < NTOK - 1) ? fabsf(rowsum[t] + colsum[t] - 1.f) : 0.f;
    for (int off = 32; off; off >>= 1) { cls += __shfl_down(cls, off); ee += __shfl_down(ee, off); }
    __shared__ float rc[6], re[6];
    int w = t >> 6;
    if ((t & 63) == 0) { rc[w] = cls; re[w] = ee; }
    __syncthreads();
    if (t == 0) {
        float a = 0.f, b = 0.f;
        for (int k = 0; k < 6; ++k) { a += rc[k]; b += re[k]; }
        out[NTOK * NTOK * 2 + 0] = a;
        out[NTOK * NTOK * 2 + 1] = b;
    }
}

// ---------------------------------------------------------------------------
// host-side encoder driver (bf16 MFMA path)
// ---------------------------------------------------------------------------
static void run_encoder(float* x, unsigned short* xb, int d,
                        const unsigned short* wq, const unsigned short* wo,
                        const unsigned short* w1, const unsigned short* w2,
                        const float* qkv_b, const float* out_b,
                        const float* ln1_s, const float* ln1_b,
                        const float* ff1_b, const float* ff2_b,
                        const float* ln2_s, const float* ln2_b,
                        unsigned short* qkvb, float* sc, unsigned short* attnb,
                        unsigned short* vtb, unsigned short* ob,
                        unsigned short* t1b, float* t2,
                        hipStream_t stream)
{
    const int dq = 3 * d;
    const int hd = d / HEADS;
    const float scale = 1.0f / sqrtf((float)hd);
    for (int l = 0; l < 2; ++l) {
        // qkv (bf16 out)
        gemm_mfma_nt<<<dim3(dq / 64, 6, 1), 256, 0, stream>>>(
            xb, wq + (long)l * dq * d, qkv_b + l * dq, qkvb,
            NTOK, dq, d, d, d, dq, 0, 0, 0, 0, 1);
        // scores = q @ k^T (fp32 out), batched over heads
        gemm_mfma_nt<<<dim3(NTOK / 64, 6, HEADS), 256, 0, stream>>>(
            qkvb, qkvb + d, nullptr, sc,
            NTOK, NTOK, hd, dq, dq, NTOK,
            (long)hd, (long)hd, (long)NTOK * NTOK, 0, 0);
        softmax_rows<<<HEADS * NTOK, 64, 0, stream>>>(sc, attnb, scale);
        transpose_v<<<dim3(d / 32, NTOK / 32), dim3(32, 32), 0, stream>>>(qkvb, vtb, d);
        // o = attn @ v (bf16 out), batched over heads
        gemm_mfma_nt<<<dim3(hd / 64, 6, HEADS), 256, 0, stream>>>(
            attnb, vtb, nullptr, ob,
            NTOK, hd, NTOK, NTOK, NTOK, d,
            (long)NTOK * NTOK, (long)hd * NTOK, (long)hd, 0, 1);
        // out-proj (fp32 out) + LN
        gemm_mfma_nt<<<dim3(d / 64, 6, 1), 256, 0, stream>>>(
            ob, wo + (long)l * d * d, out_b + l * d, t2,
            NTOK, d, d, d, d, d, 0, 0, 0, 0, 0);
        add_ln<<<NTOK, 256, 0, stream>>>(x, xb, t2, ln1_s + l * d, ln1_b + l * d, d);
        // ff1 (relu, bf16 out), ff2 (fp32 out) + LN
        gemm_mfma_nt<<<dim3(2048 / 64, 6, 1), 256, 0, stream>>>(
            xb, w1 + (long)l * 2048 * d, ff1_b + l * 2048, t1b,
            NTOK, 2048, d, d, d, 2048, 0, 0, 0, 1, 1);
        gemm_mfma_nt<<<dim3(d / 64, 6, 1), 256, 0, stream>>>(
            t1b, w2 + (long)l * d * 2048, ff2_b + l * d, t2,
            NTOK, d, 2048, 2048, 2048, d, 0, 0, 0, 0, 0);
        add_ln<<<NTOK, 256, 0, stream>>>(x, xb, t2, ln2_s + l * d, ln2_b + l * d, d);
    }
}

extern "C" void kernel_launch(void* const* d_in, const int* in_sizes, int n_in,
                              void* d_out, int out_size, void* d_ws, size_t ws_size,
                              hipStream_t stream)
{
    const float* text_emb   = (const float*)d_in[0];
    const float* vision_emb = (const float*)d_in[1];
    const int*   gt         = (const int*)  d_in[2];
    const float* t_qkv_w = (const float*)d_in[3];
    const float* t_qkv_b = (const float*)d_in[4];
    const float* t_out_w = (const float*)d_in[5];
    const float* t_out_b = (const float*)d_in[6];
    const float* t_ln1_s = (const float*)d_in[7];
    const float* t_ln1_b = (const float*)d_in[8];
    const float* t_ff1_w = (const float*)d_in[9];
    const float* t_ff1_b = (const float*)d_in[10];
    const float* t_ff2_w = (const float*)d_in[11];
    const float* t_ff2_b = (const float*)d_in[12];
    const float* t_ln2_s = (const float*)d_in[13];
    const float* t_ln2_b = (const float*)d_in[14];
    const float* c_qkv_w = (const float*)d_in[15];
    const float* c_qkv_b = (const float*)d_in[16];
    const float* c_out_w = (const float*)d_in[17];
    const float* c_out_b = (const float*)d_in[18];
    const float* c_ln1_s = (const float*)d_in[19];
    const float* c_ln1_b = (const float*)d_in[20];
    const float* c_ff1_w = (const float*)d_in[21];
    const float* c_ff1_b = (const float*)d_in[22];
    const float* c_ff2_w = (const float*)d_in[23];
    const float* c_ff2_b = (const float*)d_in[24];
    const float* c_ln2_s = (const float*)d_in[25];
    const float* c_ln2_b = (const float*)d_in[26];
    const float* lin_w   = (const float*)d_in[27];
    const float* lin_b   = (const float*)d_in[28];
    float* out = (float*)d_out;

    // ---- workspace layout ----
    float* ws = (float*)d_ws;
    float* xt      = ws;                 // 384*768
    float* all     = xt + 294912;        // 384*1536
    float* sc      = all + 589824;       // 4*384*384
    float* t2      = sc + 589824;        // 384*1536 (max)
    float* abuf    = t2 + 589824;        // 384*2
    float* cbuf    = abuf + 768;
    float* rowsum  = cbuf + 768;
    float* rowcell = rowsum + 384;
    float* colsum  = rowcell + 384;      // +384 -> total fp32 = 2066784
    unsigned short* ub = (unsigned short*)(ws + 2066784);
    unsigned short* xtb   = ub;                  // 294912
    unsigned short* allb  = xtb + 294912;        // 589824
    unsigned short* qkvb  = allb + 589824;       // 384*4608
    unsigned short* attnb = qkvb + 1769472;      // 589824
    unsigned short* vtb   = attnb + 589824;      // 1536*384
    unsigned short* ob    = vtb + 589824;        // 589824
    unsigned short* t1b   = ob + 589824;         // 384*2048
    unsigned short* wb    = t1b + 786432;        // 42467328 (all weights bf16)

    // ---- weight conversion (one fused launch) ----
    convert_weights<<<(WTOT / 4 + 255) / 256, 256, 0, stream>>>(
        t_qkv_w, t_out_w, t_ff1_w, t_ff2_w,
        c_qkv_w, c_out_w, c_ff1_w, c_ff2_w, wb);

    // ---- text encoder (d = 768) ----
    initx_k<<<(294912 + 255) / 256, 256, 0, stream>>>(text_emb, xt, xtb, 294912);
    run_encoder(xt, xtb, 768,
                wb + WO0, wb + WO1, wb + WO2, wb + WO3,
                t_qkv_b, t_out_b, t_ln1_s, t_ln1_b,
                t_ff1_b, t_ff2_b, t_ln2_s, t_ln2_b,
                qkvb, sc, attnb, vtb, ob, t1b, t2, stream);

    // ---- concat -> combined encoder (d = 1536) ----
    concat_k<<<(589824 + 255) / 256, 256, 0, stream>>>(xt, vision_emb, all, allb);
    run_encoder(all, allb, 1536,
                wb + WO4, wb + WO5, wb + WO6, wb + WO7,
                c_qkv_b, c_out_b, c_ln1_s, c_ln1_b,
                c_ff1_b, c_ff2_b, c_ln2_s, c_ln2_b,
                qkvb, sc, attnb, vtb, ob, t1b, t2, stream);

    // ---- head ----
    head_ac<<<NTOK, 256, 0, stream>>>(all, lin_w, lin_b, abuf, cbuf);
    head_probs<<<NTOK, 384, 0, stream>>>(abuf, cbuf, gt, out, rowsum, rowcell);
    colsum_k<<<NTOK, 64, 0, stream>>>(out, colsum);
    finalize_k<<<1, 384, 0, stream>>>(rowcell, rowsum, colsum, out);
}